// Round 5
// baseline (1809.863 us; speedup 1.0000x reference)
//
#include <hip/hip_runtime.h>
#include <hip/hip_bf16.h>
#include <hip/hip_fp16.h>
#include <stdint.h>

#define NTOK   8192
#define DM     2048
#define NEXP   8
#define HR     1024
#define HS     8192
#define ROWS_MAX 17408   // 16384 + 8*127 rounded up to 128

typedef _Float16 f16;
typedef f16  f16x8 __attribute__((ext_vector_type(8)));
typedef float f32x4 __attribute__((ext_vector_type(4)));

#define GLP(p) ((const __attribute__((address_space(1))) void*)(p))
#define LDP(p) ((__attribute__((address_space(3))) void*)(p))

static __device__ __forceinline__ float silu_f(float v) {
  return v / (1.0f + __expf(-v));
}

// bijective XCD-chunk swizzle (m204 form)
static __device__ __forceinline__ int xcd_swz(int bid, int nwg) {
  const int q = nwg >> 3, r = nwg & 7;
  const int x = bid & 7, i = bid >> 3;
  return (x < r ? x * (q + 1) : r * (q + 1) + (x - r) * q) + i;
}

// ---------------- conversion kernels ----------------

__global__ __launch_bounds__(256)
void conv_x_kernel(const float* __restrict__ in, f16* __restrict__ out, int n8) {
  const int i = blockIdx.x * 256 + threadIdx.x;
  if (i >= n8) return;
  const float4* p = (const float4*)in + (size_t)i * 2;
  const float4 a = p[0], b = p[1];
  f16x8 o;
  o[0] = (f16)a.x; o[1] = (f16)a.y; o[2] = (f16)a.z; o[3] = (f16)a.w;
  o[4] = (f16)b.x; o[5] = (f16)b.y; o[6] = (f16)b.z; o[7] = (f16)b.w;
  ((f16x8*)out)[i] = o;
}

// f32 [b][R][C] -> f16 [b][C][R]  (out expert stride = ostride elems)
__global__ __launch_bounds__(256)
void conv_t_kernel(const float* __restrict__ in, f16* __restrict__ out,
                   int R, int C, size_t ostride) {
  __shared__ float t[32][33];
  const int b = blockIdx.z;
  const float* inb = in + (size_t)b * R * C;
  f16* outb = out + (size_t)b * ostride;
  const int c0 = blockIdx.x * 32, r0 = blockIdx.y * 32;
  const int tx = threadIdx.x, ty0 = threadIdx.y;
#pragma unroll
  for (int yy = 0; yy < 4; ++yy) {
    const int ty = ty0 + yy * 8;
    t[ty][tx] = inb[(size_t)(r0 + ty) * C + (c0 + tx)];
  }
  __syncthreads();
#pragma unroll
  for (int yy = 0; yy < 4; ++yy) {
    const int ty = ty0 + yy * 8;
    outb[(size_t)(c0 + ty) * R + (r0 + tx)] = (f16)t[tx][ty];
  }
}

// ---------------- gating ----------------

__global__ __launch_bounds__(256)
void gate_kernel(const float* __restrict__ x, const float* __restrict__ wgate,
                 float* __restrict__ gateW, int* __restrict__ gateI,
                 float* __restrict__ importance, int* __restrict__ cnt) {
  __shared__ float impl[NEXP];
  __shared__ int cntl[NEXP];
  const int tid = threadIdx.x, lane = tid & 63, wid = tid >> 6;
  if (tid < NEXP) { impl[tid] = 0.f; cntl[tid] = 0; }
  __syncthreads();
  for (int s = 0; s < 8; ++s) {
    const int t = blockIdx.x * 32 + wid * 8 + s;
    const float* xr = x + (size_t)t * DM;
    float pv[NEXP] = {0.f, 0.f, 0.f, 0.f, 0.f, 0.f, 0.f, 0.f};
    for (int j = 0; j < DM / 64; ++j) {
      const int c = lane + j * 64;
      const float xv = xr[c];
#pragma unroll
      for (int e = 0; e < NEXP; ++e) pv[e] += xv * wgate[e * DM + c];
    }
#pragma unroll
    for (int e = 0; e < NEXP; ++e) {
#pragma unroll
      for (int st = 32; st >= 1; st >>= 1) pv[e] += __shfl_xor(pv[e], st);
    }
    if (lane == 0) {
      float v1 = pv[0]; int i1 = 0;
#pragma unroll
      for (int e = 1; e < NEXP; ++e) if (pv[e] > v1) { v1 = pv[e]; i1 = e; }
      float v2 = -1e30f; int i2 = 0;
#pragma unroll
      for (int e = 0; e < NEXP; ++e) if (e != i1 && pv[e] > v2) { v2 = pv[e]; i2 = e; }
      const float g1 = 1.f / (1.f + expf(v2 - v1));
      gateW[t * 2 + 0] = g1;  gateW[t * 2 + 1] = 1.f - g1;
      gateI[t * 2 + 0] = i1;  gateI[t * 2 + 1] = i2;
      float mx = pv[0];
#pragma unroll
      for (int e = 1; e < NEXP; ++e) mx = fmaxf(mx, pv[e]);
      float sum = 0.f, ex[NEXP];
#pragma unroll
      for (int e = 0; e < NEXP; ++e) { ex[e] = expf(pv[e] - mx); sum += ex[e]; }
      const float inv = 1.f / sum;
#pragma unroll
      for (int e = 0; e < NEXP; ++e) atomicAdd(&impl[e], ex[e] * inv);
      atomicAdd(&cntl[i1], 1);
      atomicAdd(&cntl[i2], 1);
    }
  }
  __syncthreads();
  if (tid < NEXP) {
    atomicAdd(&importance[tid], impl[tid]);
    atomicAdd(&cnt[tid], cntl[tid]);
  }
}

__global__ void scan_kernel(const int* __restrict__ cnt, int* __restrict__ seg,
                            int* __restrict__ cursor, const float* __restrict__ imp,
                            float* __restrict__ lb_out) {
  if (threadIdx.x == 0 && blockIdx.x == 0) {
    int o = 0;
#pragma unroll
    for (int e = 0; e < NEXP; ++e) {
      seg[e] = o;
      o += (cnt[e] + 127) & ~127;
      cursor[e] = 0;
    }
    seg[NEXP] = o;
    float s = 0.f;
#pragma unroll
    for (int e = 0; e < NEXP; ++e) {
      const float ce = imp[e] * ((float)NEXP / (float)NTOK);
      s += ce * ce;
    }
    *lb_out = s / (float)NEXP;
  }
}

__global__ __launch_bounds__(256)
void scatter_kernel(const float* __restrict__ gateW, const int* __restrict__ gateI,
                    const int* __restrict__ seg, int* __restrict__ cursor,
                    int* __restrict__ rowtok, float* __restrict__ rowgate) {
  const int t = blockIdx.x * 256 + threadIdx.x;
  const int lane = threadIdx.x & 63;
#pragma unroll
  for (int k = 0; k < 2; ++k) {
    const int e = gateI[t * 2 + k];
    const float g = gateW[t * 2 + k];
    for (int ee = 0; ee < NEXP; ++ee) {
      const unsigned long long m = __ballot(e == ee);
      if (e == ee) {
        const int leader = __ffsll((unsigned long long)m) - 1;
        const int rank = (int)__popcll(m & ((1ull << lane) - 1ull));
        int base = 0;
        if (lane == leader) base = atomicAdd(&cursor[ee], (int)__popcll(m));
        base = __shfl(base, leader);
        const int pos = seg[ee] + base + rank;
        rowtok[pos] = t;
        rowgate[pos] = g;
      }
    }
  }
}

// ------- m97-exact GEMM: 128x128 tile, BK=32, 256 thr, 3 waves/SIMD -------
// A: [M][K] row-major f16.  B: stored transposed [N][K] row-major f16.
// Linear LDS [128][32]; per K-step: stage(A)+stage(B) -> drain -> 16 MFMA/wave.
// Occupancy is the lever: acc[4][4]=64 AGPR + ~100 VGPR -> 3 waves/SIMD,
// co-resident waves hide the per-tile drain (m114/m97 mechanism).

__device__ __forceinline__ void stage2(const f16* __restrict__ src, int ld,
                                       f16* lds, int c0) {
  // c0 = this thread's first 16B-chunk index (0..511); chunk row=c>>2 col16=c&3
  const int r0 = c0 >> 2, k0 = (c0 & 3) * 8;
  __builtin_amdgcn_global_load_lds(GLP(src + (size_t)r0 * ld + k0), LDP(lds + c0 * 8), 16, 0, 0);
  const int c1 = c0 + 64;
  const int r1 = c1 >> 2, k1 = (c1 & 3) * 8;
  __builtin_amdgcn_global_load_lds(GLP(src + (size_t)r1 * ld + k1), LDP(lds + c1 * 8), 16, 0, 0);
}

#define GEMM128_BODY(STORE)                                                     \
  const int tid = threadIdx.x;                                                  \
  const int lane = tid & 63, wid = tid >> 6;                                    \
  const int c0 = wid * 128 + lane;                                              \
  const int wr = wid >> 1, wc = wid & 1;                                        \
  const int fr = lane & 15, fk = (lane >> 4) * 8;                               \
  f32x4 acc[4][4] = {};                                                         \
  for (int kk = 0; kk < K; kk += 32) {                                          \
    stage2(Ab + kk, K, As, c0);                                                 \
    stage2(Bb + kk, K, Bs, c0);                                                 \
    asm volatile("s_waitcnt vmcnt(0)" ::: "memory");                            \
    __syncthreads();                                                            \
    f16x8 af[4], bf[4];                                                         \
    _Pragma("unroll")                                                           \
    for (int i = 0; i < 4; ++i)                                                 \
      af[i] = *(const f16x8*)&As[(wr * 64 + i * 16 + fr) * 32 + fk];            \
    _Pragma("unroll")                                                           \
    for (int j = 0; j < 4; ++j)                                                 \
      bf[j] = *(const f16x8*)&Bs[(wc * 64 + j * 16 + fr) * 32 + fk];            \
    _Pragma("unroll")                                                           \
    for (int i = 0; i < 4; ++i)                                                 \
      _Pragma("unroll")                                                         \
      for (int j = 0; j < 4; ++j)                                               \
        acc[i][j] = __builtin_amdgcn_mfma_f32_16x16x32_f16(af[i], bf[j], acc[i][j], 0, 0, 0); \
    __syncthreads();                                                            \
  }                                                                             \
  const int r0 = (lane >> 4) * 4;                                               \
  _Pragma("unroll")                                                             \
  for (int i = 0; i < 4; ++i)                                                   \
    _Pragma("unroll")                                                           \
    for (int j = 0; j < 4; ++j)                                                 \
      _Pragma("unroll")                                                         \
      for (int r = 0; r < 4; ++r) {                                             \
        const int row = row0 + wr * 64 + i * 16 + r0 + r;                       \
        const int col = n0 + wc * 64 + j * 16 + fr;                             \
        STORE;                                                                  \
      }

// plain GEMM, f16 out (shared gate|up); gx = pow2, gxbits = log2(gx)
__global__ __launch_bounds__(256, 3)
void gemm_f16(const f16* __restrict__ A, const f16* __restrict__ B,
              f16* __restrict__ C, int gxbits, int N, int K) {
  __shared__ f16 As[128 * 32], Bs[128 * 32];
  const int lin = xcd_swz(blockIdx.x, gridDim.x);
  const int row0 = (lin & ((1 << gxbits) - 1)) << 7;   // M fastest: share B tile
  const int n0 = (lin >> gxbits) << 7;
  const f16* Ab = A + (size_t)row0 * K;
  const f16* Bb = B + (size_t)n0 * K;
  GEMM128_BODY(C[(size_t)row * N + col] = (f16)acc[i][j][r])
}

// plain GEMM, f32 out (shared down projection)
__global__ __launch_bounds__(256, 3)
void gemm_f32(const f16* __restrict__ A, const f16* __restrict__ B,
              float* __restrict__ C, int gxbits, int N, int K) {
  __shared__ f16 As[128 * 32], Bs[128 * 32];
  const int lin = xcd_swz(blockIdx.x, gridDim.x);
  const int row0 = (lin & ((1 << gxbits) - 1)) << 7;
  const int n0 = (lin >> gxbits) << 7;
  const f16* Ab = A + (size_t)row0 * K;
  const f16* Bb = B + (size_t)n0 * K;
  GEMM128_BODY(C[(size_t)row * N + col] = acc[i][j][r])
}

// routed gate|up: A rows gathered from x16 via rowtok; per-expert B [2048][DM]
__global__ __launch_bounds__(256, 3)
void gemm_rgu(const f16* __restrict__ x16, const int* __restrict__ rowtok,
              const f16* __restrict__ Wgu, f16* __restrict__ C,
              const int* __restrict__ seg) {
  __shared__ f16 As[128 * 32], Bs[128 * 32];
  const int e = blockIdx.z;
  const int row0 = seg[e] + blockIdx.y * 128;
  if (row0 >= seg[e + 1]) return;
  const int n0 = blockIdx.x * 128;
  const int K = DM;
  const f16* Bb = Wgu + (size_t)e * 2048 * DM + (size_t)n0 * K;
  const int tid = threadIdx.x;
  const int lane = tid & 63, wid = tid >> 6;
  const int c0 = wid * 128 + lane;
  const int wr = wid >> 1, wc = wid & 1;
  const int fr = lane & 15, fk = (lane >> 4) * 8;

  // per-thread gathered A source pointers (2 chunks)
  const f16* asrc[2];
#pragma unroll
  for (int i = 0; i < 2; ++i) {
    const int c = c0 + i * 64;
    int tok = rowtok[row0 + (c >> 2)];
    if (tok < 0) tok = 0;  // pad rows: junk, discarded downstream
    asrc[i] = x16 + (size_t)tok * DM + (c & 3) * 8;
  }

  f32x4 acc[4][4] = {};
  for (int kk = 0; kk < K; kk += 32) {
    __builtin_amdgcn_global_load_lds(GLP(asrc[0] + kk), LDP(As + c0 * 8), 16, 0, 0);
    __builtin_amdgcn_global_load_lds(GLP(asrc[1] + kk), LDP(As + (c0 + 64) * 8), 16, 0, 0);
    stage2(Bb + kk, K, Bs, c0);
    asm volatile("s_waitcnt vmcnt(0)" ::: "memory");
    __syncthreads();
    f16x8 af[4], bf[4];
#pragma unroll
    for (int i = 0; i < 4; ++i)
      af[i] = *(const f16x8*)&As[(wr * 64 + i * 16 + fr) * 32 + fk];
#pragma unroll
    for (int j = 0; j < 4; ++j)
      bf[j] = *(const f16x8*)&Bs[(wc * 64 + j * 16 + fr) * 32 + fk];
#pragma unroll
    for (int i = 0; i < 4; ++i)
#pragma unroll
      for (int j = 0; j < 4; ++j)
        acc[i][j] = __builtin_amdgcn_mfma_f32_16x16x32_f16(af[i], bf[j], acc[i][j], 0, 0, 0);
    __syncthreads();
  }
  const int r0 = (lane >> 4) * 4;
#pragma unroll
  for (int i = 0; i < 4; ++i)
#pragma unroll
    for (int j = 0; j < 4; ++j)
#pragma unroll
      for (int r = 0; r < 4; ++r) {
        const int row = row0 + wr * 64 + i * 16 + r0 + r;
        const int col = n0 + wc * 64 + j * 16 + fr;
        C[(size_t)row * 2048 + col] = (f16)acc[i][j][r];
      }
}

// routed down: A=hr [rows][HR], per-expert B [DM][HR], gated atomicAdd scatter
__global__ __launch_bounds__(256, 3)
void gemm_rdown(const f16* __restrict__ A, const f16* __restrict__ B,
                float* __restrict__ out, const int* __restrict__ seg,
                const int* __restrict__ rowtok, const float* __restrict__ rowgate) {
  __shared__ f16 As[128 * 32], Bs[128 * 32];
  const int e = blockIdx.z;
  const int row0 = seg[e] + blockIdx.y * 128;
  if (row0 >= seg[e + 1]) return;
  const int n0 = blockIdx.x * 128;
  const int K = HR;
  const f16* Ab = A + (size_t)row0 * K;
  const f16* Bb = B + (size_t)e * DM * HR + (size_t)n0 * K;
  const int tid = threadIdx.x;
  const int lane = tid & 63, wid = tid >> 6;
  const int c0 = wid * 128 + lane;
  const int wr = wid >> 1, wc = wid & 1;
  const int fr = lane & 15, fk = (lane >> 4) * 8;

  f32x4 acc[4][4] = {};
  for (int kk = 0; kk < K; kk += 32) {
    stage2(Ab + kk, K, As, c0);
    stage2(Bb + kk, K, Bs, c0);
    asm volatile("s_waitcnt vmcnt(0)" ::: "memory");
    __syncthreads();
    f16x8 af[4], bf[4];
#pragma unroll
    for (int i = 0; i < 4; ++i)
      af[i] = *(const f16x8*)&As[(wr * 64 + i * 16 + fr) * 32 + fk];
#pragma unroll
    for (int j = 0; j < 4; ++j)
      bf[j] = *(const f16x8*)&Bs[(wc * 64 + j * 16 + fr) * 32 + fk];
#pragma unroll
    for (int i = 0; i < 4; ++i)
#pragma unroll
      for (int j = 0; j < 4; ++j)
        acc[i][j] = __builtin_amdgcn_mfma_f32_16x16x32_f16(af[i], bf[j], acc[i][j], 0, 0, 0);
    __syncthreads();
  }

  const int r0 = (lane >> 4) * 4;
#pragma unroll
  for (int i = 0; i < 4; ++i)
#pragma unroll
    for (int r = 0; r < 4; ++r) {
      const int pos = row0 + wr * 64 + i * 16 + r0 + r;
      const int tok = rowtok[pos];
      if (tok >= 0) {
        const float gw = rowgate[pos];
#pragma unroll
        for (int j = 0; j < 4; ++j) {
          const int col = n0 + wc * 64 + j * 16 + fr;
          atomicAdd(&out[(size_t)tok * DM + col], acc[i][j][r] * gw);
        }
      }
    }
}

// ---------------- silu-mul fusion ----------------

// gu [2048][16384] (g cols 0..8191 | u cols 8192..16383) -> h [2048][8192]
__global__ __launch_bounds__(256)
void silu_shared_kernel(const f16* __restrict__ gu, f16* __restrict__ h) {
  const int idx = blockIdx.x * 256 + threadIdx.x;   // 2048*1024 items
  const int r = idx >> 10, c8 = idx & 1023;
  const f16x8 g8 = ((const f16x8*)(gu + (size_t)r * 16384))[c8];
  const f16x8 u8 = ((const f16x8*)(gu + (size_t)r * 16384 + 8192))[c8];
  f16x8 o;
#pragma unroll
  for (int j = 0; j < 8; ++j)
    o[j] = (f16)(silu_f((float)g8[j]) * (float)u8[j]);
  ((f16x8*)(h + (size_t)r * 8192))[c8] = o;
}

// gu [ROWS_MAX][2048] (g | u) -> hr [ROWS_MAX][1024]
__global__ __launch_bounds__(256)
void silu_routed_kernel(const f16* __restrict__ gu, f16* __restrict__ hr) {
  const int idx = blockIdx.x * 256 + threadIdx.x;   // ROWS_MAX*128 items
  const int r = idx >> 7, c8 = idx & 127;
  const f16x8 g8 = ((const f16x8*)(gu + (size_t)r * 2048))[c8];
  const f16x8 u8 = ((const f16x8*)(gu + (size_t)r * 2048 + 1024))[c8];
  f16x8 o;
#pragma unroll
  for (int j = 0; j < 8; ++j)
    o[j] = (f16)(silu_f((float)g8[j]) * (float)u8[j]);
  ((f16x8*)(hr + (size_t)r * 1024))[c8] = o;
}

// ---------------- host ----------------

extern "C" void kernel_launch(void* const* d_in, const int* in_sizes, int n_in,
                              void* d_out, int out_size, void* d_ws, size_t ws_size,
                              hipStream_t stream) {
  const float* x  = (const float*)d_in[0];
  const float* wg = (const float*)d_in[1];
  const float* Wg = (const float*)d_in[2];
  const float* Wu = (const float*)d_in[3];
  const float* Wd = (const float*)d_in[4];
  const float* Sg = (const float*)d_in[5];
  const float* Su = (const float*)d_in[6];
  const float* Sd = (const float*)d_in[7];
  float* out = (float*)d_out;

  char* p = (char*)d_ws;
  auto take = [&](size_t b) { char* q = p; p += (b + 255) & ~(size_t)255; return q; };
  float* importance = (float*)take(32);
  int*   cnt        = (int*)take(32);
  int*   cursor     = (int*)take(32);
  int*   seg        = (int*)take(64);
  int*   rowtok     = (int*)take((size_t)ROWS_MAX * 4);
  float* rowgate    = (float*)take((size_t)ROWS_MAX * 4);
  float* gateW      = (float*)take((size_t)NTOK * 2 * 4);
  int*   gateI      = (int*)take((size_t)NTOK * 2 * 4);
  f16* x16   = (f16*)take((size_t)NTOK * DM * 2);
  f16* SguT  = (f16*)take((size_t)2 * HS * DM * 2);       // [16384][2048]
  f16* SdT   = (f16*)take((size_t)DM * HS * 2);           // [2048][8192]
  f16* WguT  = (f16*)take((size_t)NEXP * 2048 * DM * 2);  // [e][2048][2048]
  f16* WdT   = (f16*)take((size_t)NEXP * DM * HR * 2);    // [e][2048][1024]
  f16* hbuf  = (f16*)take((size_t)4096 * HS * 2);         // h for 4096 tokens
  f16* hr    = (f16*)take((size_t)ROWS_MAX * HR * 2);     // routed h
  f16* gubuf = (f16*)take((size_t)ROWS_MAX * 2048 * 2);   // gu scratch
  if ((size_t)(p - (char*)d_ws) > ws_size) return;  // ws too small -> loud fail

  hipMemsetAsync(importance, 0, 768, stream);                 // importance+cnt+cursor
  hipMemsetAsync(rowtok, 0xFF, (size_t)ROWS_MAX * 4, stream); // -1

  conv_x_kernel<<<(NTOK * DM / 8 + 255) / 256, 256, 0, stream>>>(x, x16, NTOK * DM / 8);
  dim3 tb(32, 8);
  conv_t_kernel<<<dim3(HS / 32, DM / 32, 1), tb, 0, stream>>>(Sg, SguT, DM, HS, 0);
  conv_t_kernel<<<dim3(HS / 32, DM / 32, 1), tb, 0, stream>>>(Su, SguT + (size_t)HS * DM, DM, HS, 0);
  conv_t_kernel<<<dim3(DM / 32, HS / 32, 1), tb, 0, stream>>>(Sd, SdT, HS, DM, 0);
  conv_t_kernel<<<dim3(HR / 32, DM / 32, NEXP), tb, 0, stream>>>(Wg, WguT, DM, HR, (size_t)2048 * DM);
  conv_t_kernel<<<dim3(HR / 32, DM / 32, NEXP), tb, 0, stream>>>(Wu, WguT + (size_t)HR * DM, DM, HR, (size_t)2048 * DM);
  conv_t_kernel<<<dim3(DM / 32, HR / 32, NEXP), tb, 0, stream>>>(Wd, WdT, HR, DM, (size_t)DM * HR);

  gate_kernel<<<NTOK / 32, 256, 0, stream>>>(x, wg, gateW, gateI, importance, cnt);
  scan_kernel<<<1, 64, 0, stream>>>(cnt, seg, cursor, importance, out + (size_t)NTOK * DM);
  scatter_kernel<<<NTOK / 256, 256, 0, stream>>>(gateW, gateI, seg, cursor, rowtok, rowgate);

  // shared expert: gu in 2048-row chunks; down per 4096-row half (PLAIN stores,
  // must complete before routed down's atomicAdd accumulation)
  for (int half = 0; half < 2; ++half) {
    for (int c = 0; c < 2; ++c) {
      const f16* Ax = x16 + ((size_t)half * 4096 + (size_t)c * 2048) * DM;
      gemm_f16<<<16 * 128, 256, 0, stream>>>(Ax, SguT, gubuf, 4, 2 * HS, DM);
      silu_shared_kernel<<<2048 * 1024 / 256, 256, 0, stream>>>(gubuf, hbuf + (size_t)c * 2048 * HS);
    }
    gemm_f32<<<32 * 16, 256, 0, stream>>>(hbuf, SdT, out + (size_t)half * 4096 * DM, 5, DM, HS);
  }

  // routed experts (128-padded segments; empty tiles early-exit)
  gemm_rgu<<<dim3(2048 / 128, 136, NEXP), 256, 0, stream>>>(x16, rowtok, WguT, gubuf, seg);
  silu_routed_kernel<<<ROWS_MAX * 128 / 256, 256, 0, stream>>>(gubuf, hr);
  gemm_rdown<<<dim3(DM / 128, 136, NEXP), 256, 0, stream>>>(hr, WdT, out, seg, rowtok, rowgate);
}

// Round 6
// 1446.597 us; speedup vs baseline: 1.2511x; 1.2511x over previous
//
#include <hip/hip_runtime.h>
#include <hip/hip_bf16.h>
#include <hip/hip_fp16.h>
#include <stdint.h>

#define NTOK   8192
#define DM     2048
#define NEXP   8
#define HR     1024
#define HS     8192
#define ROWS_MAX 18432   // 16384 + 8*255 rounded up to 256

typedef _Float16 f16;
typedef f16  f16x8 __attribute__((ext_vector_type(8)));
typedef float f32x4 __attribute__((ext_vector_type(4)));

#define GLP(p) ((const __attribute__((address_space(1))) void*)(p))
#define LDP(p) ((__attribute__((address_space(3))) void*)(p))

static __device__ __forceinline__ float silu_f(float v) {
  return v / (1.0f + __expf(-v));
}

// bijective XCD-chunk swizzle (m204 form)
static __device__ __forceinline__ int xcd_swz(int bid, int nwg) {
  const int q = nwg >> 3, r = nwg & 7;
  const int x = bid & 7, i = bid >> 3;
  return (x < r ? x * (q + 1) : r * (q + 1) + (x - r) * q) + i;
}

// ---------------- conversion kernels ----------------

__global__ __launch_bounds__(256)
void conv_x_kernel(const float* __restrict__ in, f16* __restrict__ out, int n8) {
  const int i = blockIdx.x * 256 + threadIdx.x;
  if (i >= n8) return;
  const float4* p = (const float4*)in + (size_t)i * 2;
  const float4 a = p[0], b = p[1];
  f16x8 o;
  o[0] = (f16)a.x; o[1] = (f16)a.y; o[2] = (f16)a.z; o[3] = (f16)a.w;
  o[4] = (f16)b.x; o[5] = (f16)b.y; o[6] = (f16)b.z; o[7] = (f16)b.w;
  ((f16x8*)out)[i] = o;
}

// f32 [b][R][C] -> f16 [b][C][R] with optional 16-row g/u interleave.
// rmap==0: phys row = tr.  rmap==1 (g) / 2 (u): phys = ((tr>>4)<<5)+((rmap-1)<<4)+(tr&15)
__global__ __launch_bounds__(256)
void conv_t_kernel(const float* __restrict__ in, f16* __restrict__ out,
                   int R, int C, size_t ostride, int rmap) {
  __shared__ float t[32][33];
  const int b = blockIdx.z;
  const float* inb = in + (size_t)b * R * C;
  f16* outb = out + (size_t)b * ostride;
  const int c0 = blockIdx.x * 32, r0 = blockIdx.y * 32;
  const int tx = threadIdx.x, ty0 = threadIdx.y;
#pragma unroll
  for (int yy = 0; yy < 4; ++yy) {
    const int ty = ty0 + yy * 8;
    t[ty][tx] = inb[(size_t)(r0 + ty) * C + (c0 + tx)];
  }
  __syncthreads();
#pragma unroll
  for (int yy = 0; yy < 4; ++yy) {
    const int ty = ty0 + yy * 8;
    const int tr = c0 + ty;
    const int pr = rmap ? (((tr >> 4) << 5) + ((rmap - 1) << 4) + (tr & 15)) : tr;
    outb[(size_t)pr * R + (r0 + tx)] = (f16)t[tx][ty];
  }
}

// ---------------- gating ----------------

__global__ __launch_bounds__(256)
void gate_kernel(const float* __restrict__ x, const float* __restrict__ wgate,
                 float* __restrict__ gateW, int* __restrict__ gateI,
                 float* __restrict__ importance, int* __restrict__ cnt) {
  __shared__ float impl[NEXP];
  __shared__ int cntl[NEXP];
  const int tid = threadIdx.x, lane = tid & 63, wid = tid >> 6;
  if (tid < NEXP) { impl[tid] = 0.f; cntl[tid] = 0; }
  __syncthreads();
  for (int s = 0; s < 8; ++s) {
    const int t = blockIdx.x * 32 + wid * 8 + s;
    const float* xr = x + (size_t)t * DM;
    float pv[NEXP] = {0.f, 0.f, 0.f, 0.f, 0.f, 0.f, 0.f, 0.f};
    for (int j = 0; j < DM / 64; ++j) {
      const int c = lane + j * 64;
      const float xv = xr[c];
#pragma unroll
      for (int e = 0; e < NEXP; ++e) pv[e] += xv * wgate[e * DM + c];
    }
#pragma unroll
    for (int e = 0; e < NEXP; ++e) {
#pragma unroll
      for (int st = 32; st >= 1; st >>= 1) pv[e] += __shfl_xor(pv[e], st);
    }
    if (lane == 0) {
      float v1 = pv[0]; int i1 = 0;
#pragma unroll
      for (int e = 1; e < NEXP; ++e) if (pv[e] > v1) { v1 = pv[e]; i1 = e; }
      float v2 = -1e30f; int i2 = 0;
#pragma unroll
      for (int e = 0; e < NEXP; ++e) if (e != i1 && pv[e] > v2) { v2 = pv[e]; i2 = e; }
      const float g1 = 1.f / (1.f + expf(v2 - v1));
      gateW[t * 2 + 0] = g1;  gateW[t * 2 + 1] = 1.f - g1;
      gateI[t * 2 + 0] = i1;  gateI[t * 2 + 1] = i2;
      float mx = pv[0];
#pragma unroll
      for (int e = 1; e < NEXP; ++e) mx = fmaxf(mx, pv[e]);
      float sum = 0.f, ex[NEXP];
#pragma unroll
      for (int e = 0; e < NEXP; ++e) { ex[e] = expf(pv[e] - mx); sum += ex[e]; }
      const float inv = 1.f / sum;
#pragma unroll
      for (int e = 0; e < NEXP; ++e) atomicAdd(&impl[e], ex[e] * inv);
      atomicAdd(&cntl[i1], 1);
      atomicAdd(&cntl[i2], 1);
    }
  }
  __syncthreads();
  if (tid < NEXP) {
    atomicAdd(&importance[tid], impl[tid]);
    atomicAdd(&cnt[tid], cntl[tid]);
  }
}

__global__ void scan_kernel(const int* __restrict__ cnt, int* __restrict__ seg,
                            int* __restrict__ cursor, const float* __restrict__ imp,
                            float* __restrict__ lb_out) {
  if (threadIdx.x == 0 && blockIdx.x == 0) {
    int o = 0;
#pragma unroll
    for (int e = 0; e < NEXP; ++e) {
      seg[e] = o;
      o += (cnt[e] + 255) & ~255;
      cursor[e] = 0;
    }
    seg[NEXP] = o;
    float s = 0.f;
#pragma unroll
    for (int e = 0; e < NEXP; ++e) {
      const float ce = imp[e] * ((float)NEXP / (float)NTOK);
      s += ce * ce;
    }
    *lb_out = s / (float)NEXP;
  }
}

__global__ __launch_bounds__(256)
void scatter_kernel(const float* __restrict__ gateW, const int* __restrict__ gateI,
                    const int* __restrict__ seg, int* __restrict__ cursor,
                    int* __restrict__ rowtok, float* __restrict__ rowgate) {
  const int t = blockIdx.x * 256 + threadIdx.x;
  const int lane = threadIdx.x & 63;
#pragma unroll
  for (int k = 0; k < 2; ++k) {
    const int e = gateI[t * 2 + k];
    const float g = gateW[t * 2 + k];
    for (int ee = 0; ee < NEXP; ++ee) {
      const unsigned long long m = __ballot(e == ee);
      if (e == ee) {
        const int leader = __ffsll((unsigned long long)m) - 1;
        const int rank = (int)__popcll(m & ((1ull << lane) - 1ull));
        int base = 0;
        if (lane == leader) base = atomicAdd(&cursor[ee], (int)__popcll(m));
        base = __shfl(base, leader);
        const int pos = seg[ee] + base + rank;
        rowtok[pos] = t;
        rowgate[pos] = g;
      }
    }
  }
}

// ---------------- 256x256 GEMM, BK=64, dbuf LDS, T2 read-swizzle ----------------
// (R3-verified structure.)  A: [M][K] row-major f16 (per-thread pre-swizzled
// source rows).  B: stored transposed [N][K] row-major f16.
// LDS tile: logical [256][64] f16; stored with byte ^= ((row&7)<<4);
// global_load_lds writes LINEAR, inverse swizzle pre-applied to the per-lane
// GLOBAL source address (rule #21), reads apply the same XOR.

struct G8Ptrs { const f16* a[4]; const f16* b[4]; };

// thread's i-th staging instr: linear LDS byte L -> logical (row r, col c)
static __device__ __forceinline__ void swz_rc(int tid, int i, int& r, int& c) {
  const int L = i * 8192 + tid * 16;
  const int U = L ^ (((L >> 7) & 7) << 4);
  r = U >> 7;
  c = (U & 127) >> 1;
}

static __device__ __forceinline__ void stage8(const G8Ptrs& P, int koff,
                                              f16* AsB, f16* BsB, int wid) {
#pragma unroll
  for (int i = 0; i < 4; ++i) {
    __builtin_amdgcn_global_load_lds(GLP(P.a[i] + koff), LDP(AsB + i * 4096 + wid * 512), 16, 0, 0);
    __builtin_amdgcn_global_load_lds(GLP(P.b[i] + koff), LDP(BsB + i * 4096 + wid * 512), 16, 0, 0);
  }
}

static __device__ __forceinline__ void g8_mainloop(const G8Ptrs& P, int nt,
                                                   f16* As, f16* Bs,
                                                   f32x4 (&acc)[8][4]) {
  const int tid = threadIdx.x;
  const int lane = tid & 63, wid = tid >> 6;
  const int wr = wid >> 2, wc = wid & 3;
  const int fr = lane & 15, fk = (lane >> 4) * 8;

  stage8(P, 0, As, Bs, wid);
  asm volatile("s_waitcnt vmcnt(0)" ::: "memory");
  __syncthreads();

  for (int t = 0; t < nt; ++t) {
    const int cur = t & 1;
    if (t + 1 < nt)
      stage8(P, (t + 1) * 64, As + (cur ^ 1) * 16384, Bs + (cur ^ 1) * 16384, wid);
    const f16* Ab = As + cur * 16384;
    const f16* Bb = Bs + cur * 16384;
    f16x8 bf[4][2];
#pragma unroll
    for (int n = 0; n < 4; ++n) {
      const int r = wc * 64 + n * 16 + fr;
      const int sw = (r & 7) << 3;
#pragma unroll
      for (int ks = 0; ks < 2; ++ks)
        bf[n][ks] = *(const f16x8*)&Bb[(r * 64 + ks * 32 + fk) ^ sw];
    }
#pragma unroll
    for (int mh = 0; mh < 2; ++mh) {
#pragma unroll
      for (int ks = 0; ks < 2; ++ks) {
        f16x8 af[4];
#pragma unroll
        for (int m = 0; m < 4; ++m) {
          const int r = wr * 128 + (mh * 4 + m) * 16 + fr;
          af[m] = *(const f16x8*)&Ab[(r * 64 + ks * 32 + fk) ^ ((r & 7) << 3)];
        }
#pragma unroll
        for (int m = 0; m < 4; ++m)
#pragma unroll
          for (int n = 0; n < 4; ++n)
            acc[mh * 4 + m][n] =
                __builtin_amdgcn_mfma_f32_16x16x32_f16(af[m], bf[n][ks], acc[mh * 4 + m][n], 0, 0, 0);
      }
    }
    asm volatile("s_waitcnt vmcnt(0)" ::: "memory");
    __syncthreads();
  }
}

// fused gate|up GEMM + silu epilogue -> f16 H.
// B is 16-col g/u interleaved: frag n=2k holds g, n=2k+1 holds u of the SAME
// h-columns -> h = silu(acc[m][2k]) * acc[m][2k+1], coalesced f16 stores.
__global__ __launch_bounds__(512, 2)
void g8_gu(const f16* __restrict__ A, const f16* __restrict__ B,
           f16* __restrict__ H, int gx, int Nh, int K) {
  __shared__ f16 As[2 * 16384], Bs[2 * 16384];
  const int lin = xcd_swz(blockIdx.x, gridDim.x);
  const int row0 = (lin % gx) * 256, n0 = (lin / gx) * 256;
  const int tid = threadIdx.x;
  G8Ptrs P;
#pragma unroll
  for (int i = 0; i < 4; ++i) {
    int r, c; swz_rc(tid, i, r, c);
    P.a[i] = A + (size_t)(row0 + r) * K + c;
    P.b[i] = B + (size_t)(n0 + r) * K + c;
  }
  f32x4 acc[8][4] = {};
  g8_mainloop(P, K / 64, As, Bs, acc);
  const int lane = tid & 63, wid = tid >> 6;
  const int wr = wid >> 2, wc = wid & 3;
  const int fr = lane & 15, r0 = (lane >> 4) * 4;
  const int hc0 = (n0 + wc * 64) >> 1;
#pragma unroll
  for (int m = 0; m < 8; ++m)
#pragma unroll
    for (int k = 0; k < 2; ++k)
#pragma unroll
      for (int rr = 0; rr < 4; ++rr) {
        const int row = row0 + wr * 128 + m * 16 + r0 + rr;
        const int hcol = hc0 + k * 16 + fr;
        const float g = acc[m][2 * k][rr];
        const float u = acc[m][2 * k + 1][rr];
        H[(size_t)row * Nh + hcol] = (f16)(silu_f(g) * u);
      }
}

// shared down: plain f32 stores (runs before routed down's atomic accumulation)
__global__ __launch_bounds__(512, 2)
void g8_down(const f16* __restrict__ A, const f16* __restrict__ B,
             float* __restrict__ out, int gx, int N, int K) {
  __shared__ f16 As[2 * 16384], Bs[2 * 16384];
  const int lin = xcd_swz(blockIdx.x, gridDim.x);
  const int row0 = (lin % gx) * 256, n0 = (lin / gx) * 256;
  const int tid = threadIdx.x;
  G8Ptrs P;
#pragma unroll
  for (int i = 0; i < 4; ++i) {
    int r, c; swz_rc(tid, i, r, c);
    P.a[i] = A + (size_t)(row0 + r) * K + c;
    P.b[i] = B + (size_t)(n0 + r) * K + c;
  }
  f32x4 acc[8][4] = {};
  g8_mainloop(P, K / 64, As, Bs, acc);
  const int lane = tid & 63, wid = tid >> 6;
  const int wr = wid >> 2, wc = wid & 3;
  const int fr = lane & 15, r0 = (lane >> 4) * 4;
#pragma unroll
  for (int m = 0; m < 8; ++m)
#pragma unroll
    for (int n = 0; n < 4; ++n)
#pragma unroll
      for (int rr = 0; rr < 4; ++rr) {
        const int row = row0 + wr * 128 + m * 16 + r0 + rr;
        const int col = n0 + wc * 64 + n * 16 + fr;
        out[(size_t)row * N + col] = acc[m][n][rr];
      }
}

// routed gate|up + fused silu: A rows gathered from x16 via rowtok; per-expert
// interleaved B [2048][DM]; writes hr [rows][HR] directly.
__global__ __launch_bounds__(512, 2)
void g8_rgu(const f16* __restrict__ x16, const int* __restrict__ rowtok,
            const f16* __restrict__ Wgu, f16* __restrict__ hr,
            const int* __restrict__ seg) {
  __shared__ f16 As[2 * 16384], Bs[2 * 16384];
  const int e = blockIdx.z;
  const int row0 = seg[e] + blockIdx.y * 256;
  if (row0 >= seg[e + 1]) return;
  const int n0 = blockIdx.x * 256;
  const f16* Bbase = Wgu + (size_t)e * 2048 * DM;
  const int tid = threadIdx.x;
  G8Ptrs P;
#pragma unroll
  for (int i = 0; i < 4; ++i) {
    int r, c; swz_rc(tid, i, r, c);
    int tok = rowtok[row0 + r];
    if (tok < 0) tok = 0;   // pad rows: junk, discarded downstream
    P.a[i] = x16 + (size_t)tok * DM + c;
    P.b[i] = Bbase + (size_t)(n0 + r) * DM + c;
  }
  f32x4 acc[8][4] = {};
  g8_mainloop(P, DM / 64, As, Bs, acc);
  const int lane = tid & 63, wid = tid >> 6;
  const int wr = wid >> 2, wc = wid & 3;
  const int fr = lane & 15, r0 = (lane >> 4) * 4;
  const int hc0 = (n0 + wc * 64) >> 1;
#pragma unroll
  for (int m = 0; m < 8; ++m)
#pragma unroll
    for (int k = 0; k < 2; ++k)
#pragma unroll
      for (int rr = 0; rr < 4; ++rr) {
        const int row = row0 + wr * 128 + m * 16 + r0 + rr;
        const int hcol = hc0 + k * 16 + fr;
        const float g = acc[m][2 * k][rr];
        const float u = acc[m][2 * k + 1][rr];
        hr[(size_t)row * HR + hcol] = (f16)(silu_f(g) * u);
      }
}

// routed down: A=hr [rows][HR], per-expert B [DM][HR], gated atomicAdd scatter
__global__ __launch_bounds__(512, 2)
void g8_rdown(const f16* __restrict__ A, const f16* __restrict__ B,
              float* __restrict__ out, const int* __restrict__ seg,
              const int* __restrict__ rowtok, const float* __restrict__ rowgate) {
  __shared__ f16 As[2 * 16384], Bs[2 * 16384];
  const int e = blockIdx.z;
  const int row0 = seg[e] + blockIdx.y * 256;
  if (row0 >= seg[e + 1]) return;
  const int n0 = blockIdx.x * 256;
  const f16* Bbase = B + (size_t)e * DM * HR;
  const int tid = threadIdx.x;
  G8Ptrs P;
#pragma unroll
  for (int i = 0; i < 4; ++i) {
    int r, c; swz_rc(tid, i, r, c);
    P.a[i] = A + (size_t)(row0 + r) * HR + c;
    P.b[i] = Bbase + (size_t)(n0 + r) * HR + c;
  }
  f32x4 acc[8][4] = {};
  g8_mainloop(P, HR / 64, As, Bs, acc);
  const int lane = tid & 63, wid = tid >> 6;
  const int wr = wid >> 2, wc = wid & 3;
  const int fr = lane & 15, r0 = (lane >> 4) * 4;
#pragma unroll
  for (int m = 0; m < 8; ++m)
#pragma unroll
    for (int rr = 0; rr < 4; ++rr) {
      const int pos = row0 + wr * 128 + m * 16 + r0 + rr;
      const int tok = rowtok[pos];
      if (tok >= 0) {
        const float gw = rowgate[pos];
#pragma unroll
        for (int n = 0; n < 4; ++n) {
          const int col = n0 + wc * 64 + n * 16 + fr;
          atomicAdd(&out[(size_t)tok * DM + col], acc[m][n][rr] * gw);
        }
      }
    }
}

// ---------------- host ----------------

extern "C" void kernel_launch(void* const* d_in, const int* in_sizes, int n_in,
                              void* d_out, int out_size, void* d_ws, size_t ws_size,
                              hipStream_t stream) {
  const float* x  = (const float*)d_in[0];
  const float* wg = (const float*)d_in[1];
  const float* Wg = (const float*)d_in[2];
  const float* Wu = (const float*)d_in[3];
  const float* Wd = (const float*)d_in[4];
  const float* Sg = (const float*)d_in[5];
  const float* Su = (const float*)d_in[6];
  const float* Sd = (const float*)d_in[7];
  float* out = (float*)d_out;

  char* p = (char*)d_ws;
  auto take = [&](size_t b) { char* q = p; p += (b + 255) & ~(size_t)255; return q; };
  float* importance = (float*)take(32);
  int*   cnt        = (int*)take(32);
  int*   cursor     = (int*)take(32);
  int*   seg        = (int*)take(64);
  int*   rowtok     = (int*)take((size_t)ROWS_MAX * 4);
  float* rowgate    = (float*)take((size_t)ROWS_MAX * 4);
  float* gateW      = (float*)take((size_t)NTOK * 2 * 4);
  int*   gateI      = (int*)take((size_t)NTOK * 2 * 4);
  f16* x16   = (f16*)take((size_t)NTOK * DM * 2);
  f16* SguI  = (f16*)take((size_t)2 * HS * DM * 2);       // [16384][2048] g/u 16-interleaved
  f16* SdT   = (f16*)take((size_t)DM * HS * 2);           // [2048][8192]
  f16* WguI  = (f16*)take((size_t)NEXP * 2048 * DM * 2);  // [e][2048][2048] interleaved
  f16* WdT   = (f16*)take((size_t)NEXP * DM * HR * 2);    // [e][2048][1024]
  f16* hbuf  = (f16*)take((size_t)NTOK * HS * 2);         // h for all 8192 tokens (128 MB)
  f16* hr    = (f16*)take((size_t)ROWS_MAX * HR * 2);     // routed h
  if ((size_t)(p - (char*)d_ws) > ws_size) return;  // ws too small -> loud fail

  hipMemsetAsync(importance, 0, 768, stream);                 // importance+cnt+cursor
  hipMemsetAsync(rowtok, 0xFF, (size_t)ROWS_MAX * 4, stream); // -1

  conv_x_kernel<<<(NTOK * DM / 8 + 255) / 256, 256, 0, stream>>>(x, x16, NTOK * DM / 8);
  dim3 tb(32, 8);
  conv_t_kernel<<<dim3(HS / 32, DM / 32, 1), tb, 0, stream>>>(Sg, SguI, DM, HS, 0, 1);
  conv_t_kernel<<<dim3(HS / 32, DM / 32, 1), tb, 0, stream>>>(Su, SguI, DM, HS, 0, 2);
  conv_t_kernel<<<dim3(DM / 32, HS / 32, 1), tb, 0, stream>>>(Sd, SdT, HS, DM, 0, 0);
  conv_t_kernel<<<dim3(HR / 32, DM / 32, NEXP), tb, 0, stream>>>(Wg, WguI, DM, HR, (size_t)2048 * DM, 1);
  conv_t_kernel<<<dim3(HR / 32, DM / 32, NEXP), tb, 0, stream>>>(Wu, WguI, DM, HR, (size_t)2048 * DM, 2);
  conv_t_kernel<<<dim3(DM / 32, HR / 32, NEXP), tb, 0, stream>>>(Wd, WdT, HR, DM, (size_t)DM * HR, 0);

  gate_kernel<<<NTOK / 32, 256, 0, stream>>>(x, wg, gateW, gateI, importance, cnt);
  scan_kernel<<<1, 64, 0, stream>>>(cnt, seg, cursor, importance, out + (size_t)NTOK * DM);
  scatter_kernel<<<NTOK / 256, 256, 0, stream>>>(gateW, gateI, seg, cursor, rowtok, rowgate);

  // routed gate|up (+silu fused)  [256-padded segments; empty tiles early-exit]
  g8_rgu<<<dim3(8, 64, NEXP), 512, 0, stream>>>(x16, rowtok, WguI, hr, seg);

  // shared expert: one gu dispatch (M=8192), one down dispatch (plain stores)
  g8_gu<<<32 * 64, 512, 0, stream>>>(x16, SguI, hbuf, 32, HS, DM);
  g8_down<<<32 * 8, 512, 0, stream>>>(hbuf, SdT, out, 32, DM, HS);

  // routed down accumulates on top of the shared result (stream-ordered)
  g8_rdown<<<dim3(8, 64, NEXP), 512, 0, stream>>>(hr, WdT, out, seg, rowtok, rowgate);
}